// Round 2
// 223.106 us; speedup vs baseline: 1.0103x; 1.0103x over previous
//
#include <hip/hip_runtime.h>

// cov = R * diag(s^2) * R^T per gaussian (COLMAP quat convention, no normalize).
// Memory-bound: 28 B in + 36 B out per gaussian (256 MB total @ N=4M).
// v3: v2 with compile fix — nontemporal stores need a native clang vector
//     type, not HIP_vector_type<float,4>.

constexpr int TPB = 256;

typedef float f32x4 __attribute__((ext_vector_type(4)));

__global__ __launch_bounds__(TPB) void gaussian_cov_kernel(
    const float4* __restrict__ quat,   // [N] as (w,x,y,z)
    const float*  __restrict__ scales, // [N*3]
    float*        __restrict__ out,    // [N*9]
    int N) {
    __shared__ __align__(16) float sOut[TPB * 9];  // 9216 B output staging
    __shared__ __align__(16) float sScl[TPB * 3];  // 3072 B scales staging

    const int t   = threadIdx.x;
    const int blk = blockIdx.x;
    const int i   = blk * TPB + t;

    // ---- Cooperative scales stage: 768 floats = 192 aligned float4 loads.
    // Block base (blk*768 floats = 3072 B) is 16B-aligned.
    const int sclBase = blk * (TPB * 3);
    const int sclTot  = N * 3;
    if (t < (TPB * 3) / 4) {
        const int f = sclBase + t * 4;
        if (f + 4 <= sclTot) {
            reinterpret_cast<f32x4*>(sScl)[t] =
                reinterpret_cast<const f32x4*>(scales + sclBase)[t];
        } else {
#pragma unroll
            for (int k = 0; k < 4; ++k)
                if (f + k < sclTot) sScl[t * 4 + k] = scales[f + k];
        }
    }

    // Quat load overlaps the scales stage (no LDS dependency yet).
    float4 q = make_float4(0.f, 0.f, 0.f, 0.f);
    if (i < N) q = quat[i];

    __syncthreads();

    if (i < N) {
        const float w = q.x, x = q.y, y = q.z, z = q.w;
        const float sx = sScl[t * 3 + 0];   // stride-3 (odd) -> 2 lanes/bank, free
        const float sy = sScl[t * 3 + 1];
        const float sz = sScl[t * 3 + 2];

        const float xx = 2.0f * x * x, yy = 2.0f * y * y, zz = 2.0f * z * z;
        const float xy = 2.0f * x * y, xz = 2.0f * x * z, yz = 2.0f * y * z;
        const float wx = 2.0f * w * x, wy = 2.0f * w * y, wz = 2.0f * w * z;

        const float R00 = 1.0f - yy - zz, R01 = xy - wz, R02 = xz + wy;
        const float R10 = xy + wz, R11 = 1.0f - xx - zz, R12 = yz - wx;
        const float R20 = xz - wy, R21 = yz + wx, R22 = 1.0f - xx - yy;

        const float s2x = sx * sx, s2y = sy * sy, s2z = sz * sz;

        // cov[i][j] = sum_k R[i][k]*R[j][k]*s2[k]  (symmetric)
        const float c00 = R00 * R00 * s2x + R01 * R01 * s2y + R02 * R02 * s2z;
        const float c01 = R00 * R10 * s2x + R01 * R11 * s2y + R02 * R12 * s2z;
        const float c02 = R00 * R20 * s2x + R01 * R21 * s2y + R02 * R22 * s2z;
        const float c11 = R10 * R10 * s2x + R11 * R11 * s2y + R12 * R12 * s2z;
        const float c12 = R10 * R20 * s2x + R11 * R21 * s2y + R12 * R22 * s2z;
        const float c22 = R20 * R20 * s2x + R21 * R21 * s2y + R22 * R22 * s2z;

        float* l = &sOut[t * 9];            // stride-9 writes: 2 lanes/bank, free
        l[0] = c00; l[1] = c01; l[2] = c02;
        l[3] = c01; l[4] = c11; l[5] = c12;
        l[6] = c02; l[7] = c12; l[8] = c22;
    }

    __syncthreads();

    // ---- Output sweep. Full blocks: 576 float4 (2 full passes + 64-lane tail).
    // Block byte base = blk*9216, 16B-aligned. LDS read-back is contiguous
    // ds_read_b128 (conflict-free optimal pattern).
    const int outBase = blk * (TPB * 9);
    const int total   = N * 9;
    if (outBase + TPB * 9 <= total) {
        const f32x4* src = reinterpret_cast<const f32x4*>(sOut);
        f32x4*       dst = reinterpret_cast<f32x4*>(out + outBase);
        __builtin_nontemporal_store(src[t],         &dst[t]);
        __builtin_nontemporal_store(src[TPB + t],   &dst[TPB + t]);
        if (t < 64) {
            __builtin_nontemporal_store(src[2 * TPB + t], &dst[2 * TPB + t]);
        }
    } else {
        // Tail block: dword sweep with bounds checks.
#pragma unroll
        for (int r = 0; r < 9; ++r) {
            const int idx = r * TPB + t;
            if (outBase + idx < total) out[outBase + idx] = sOut[idx];
        }
    }
}

extern "C" void kernel_launch(void* const* d_in, const int* in_sizes, int n_in,
                              void* d_out, int out_size, void* d_ws, size_t ws_size,
                              hipStream_t stream) {
    const float4* quat   = (const float4*)d_in[0];
    const float*  scales = (const float*)d_in[1];
    float*        out    = (float*)d_out;
    const int N = in_sizes[0] / 4;
    const int blocks = (N + TPB - 1) / TPB;
    gaussian_cov_kernel<<<blocks, TPB, 0, stream>>>(quat, scales, out, N);
}

// Round 3
// 218.528 us; speedup vs baseline: 1.0315x; 1.0209x over previous
//
#include <hip/hip_runtime.h>

// cov = R * diag(s^2) * R^T per gaussian (COLMAP quat convention, no normalize).
// Memory-bound: 28 B in + 36 B out per gaussian (256 MB total @ N=4M).
// v4: barrier-free wave-local structure. Each wave owns a private LDS slice
//     for 64 gaussians (scales stage + output transpose) -> no __syncthreads
//     at all (LDS deps are wave-internal, lgkmcnt-ordered by the compiler).
//     2048-block grid-stride loop (persistent waves, no 15k-block churn).
//     Nontemporal loads AND stores (streamed once, zero reuse).

constexpr int TPB = 256;
constexpr int NW  = TPB / 64;   // waves per block

typedef float f32x4 __attribute__((ext_vector_type(4)));

__global__ __launch_bounds__(TPB) void gaussian_cov_kernel(
    const f32x4* __restrict__ quat,   // [N] as (w,x,y,z)
    const float* __restrict__ scales, // [N*3]
    float*       __restrict__ out,    // [N*9]
    int N) {
    // Wave-private slices: no cross-wave sharing anywhere.
    __shared__ __align__(16) float sOut[NW][64 * 9];  // 9216 B
    __shared__ __align__(16) float sScl[NW][64 * 3];  // 3072 B

    const int t    = threadIdx.x;
    const int lane = t & 63;
    const int w    = t >> 6;

    const int nGroups = (N + 63) >> 6;      // 64-gaussian groups
    const int gStride = gridDim.x * NW;

    for (int g = blockIdx.x * NW + w; g < nGroups; g += gStride) {
        const int base = g << 6;            // first gaussian of this group
        const int i    = base + lane;

        // ---- Wave-local scales stage: 192 floats = 48 f32x4 (lanes 0..47).
        // Group base (base*3 floats = 768 B) is 16B-aligned.
        if (lane < 48) {
            const int f = base * 3 + lane * 4;
            if (f + 4 <= N * 3) {
                reinterpret_cast<f32x4*>(sScl[w])[lane] =
                    __builtin_nontemporal_load(
                        reinterpret_cast<const f32x4*>(scales + base * 3) + lane);
            } else {
#pragma unroll
                for (int k = 0; k < 4; ++k)
                    if (f + k < N * 3) sScl[w][lane * 4 + k] = scales[f + k];
            }
        }

        f32x4 q = 0.0f;
        if (i < N) q = __builtin_nontemporal_load(quat + i);

        if (i < N) {
            const float qw = q.x, qx = q.y, qy = q.z, qz = q.w;
            const float sx = sScl[w][lane * 3 + 0];  // stride-3: 2 lanes/bank, free
            const float sy = sScl[w][lane * 3 + 1];
            const float sz = sScl[w][lane * 3 + 2];

            const float xx = 2.0f * qx * qx, yy = 2.0f * qy * qy, zz = 2.0f * qz * qz;
            const float xy = 2.0f * qx * qy, xz = 2.0f * qx * qz, yz = 2.0f * qy * qz;
            const float wx = 2.0f * qw * qx, wy = 2.0f * qw * qy, wz = 2.0f * qw * qz;

            const float R00 = 1.0f - yy - zz, R01 = xy - wz, R02 = xz + wy;
            const float R10 = xy + wz, R11 = 1.0f - xx - zz, R12 = yz - wx;
            const float R20 = xz - wy, R21 = yz + wx, R22 = 1.0f - xx - yy;

            const float s2x = sx * sx, s2y = sy * sy, s2z = sz * sz;

            // cov[i][j] = sum_k R[i][k]*R[j][k]*s2[k]  (symmetric)
            const float c00 = R00 * R00 * s2x + R01 * R01 * s2y + R02 * R02 * s2z;
            const float c01 = R00 * R10 * s2x + R01 * R11 * s2y + R02 * R12 * s2z;
            const float c02 = R00 * R20 * s2x + R01 * R21 * s2y + R02 * R22 * s2z;
            const float c11 = R10 * R10 * s2x + R11 * R11 * s2y + R12 * R12 * s2z;
            const float c12 = R10 * R20 * s2x + R11 * R21 * s2y + R12 * R22 * s2z;
            const float c22 = R20 * R20 * s2x + R21 * R21 * s2y + R22 * R22 * s2z;

            float* l = &sOut[w][lane * 9];  // stride-9: 2 lanes/bank, free
            l[0] = c00; l[1] = c01; l[2] = c02;
            l[3] = c01; l[4] = c11; l[5] = c12;
            l[6] = c02; l[7] = c12; l[8] = c22;
        }

        // ---- Wave-local output sweep: 576 floats = 144 f32x4.
        // Group byte base = g*2304, 16B-aligned. Contiguous ds_read_b128.
        if (base + 64 <= N) {
            const f32x4* src = reinterpret_cast<const f32x4*>(sOut[w]);
            f32x4*       dst = reinterpret_cast<f32x4*>(out) + (size_t)144 * g;
            __builtin_nontemporal_store(src[lane],      dst + lane);
            __builtin_nontemporal_store(src[64 + lane], dst + 64 + lane);
            if (lane < 16)
                __builtin_nontemporal_store(src[128 + lane], dst + 128 + lane);
        } else {
            // Tail group: guarded dword sweep.
#pragma unroll
            for (int r = 0; r < 9; ++r) {
                const int idx = r * 64 + lane;
                if (base * 9 + idx < N * 9) out[base * 9 + idx] = sOut[w][idx];
            }
        }
    }
}

extern "C" void kernel_launch(void* const* d_in, const int* in_sizes, int n_in,
                              void* d_out, int out_size, void* d_ws, size_t ws_size,
                              hipStream_t stream) {
    const f32x4* quat   = (const f32x4*)d_in[0];
    const float* scales = (const float*)d_in[1];
    float*       out    = (float*)d_out;
    const int N = in_sizes[0] / 4;
    const int nGroups = (N + 63) / 64;
    int blocks = (nGroups + NW - 1) / NW;
    if (blocks > 2048) blocks = 2048;     // persistent grid-stride (G11)
    gaussian_cov_kernel<<<blocks, TPB, 0, stream>>>(quat, scales, out, N);
}